// Round 1
// baseline (233.261 us; speedup 1.0000x reference)
//
#include <hip/hip_runtime.h>

typedef unsigned short u16;
typedef float f32x4 __attribute__((ext_vector_type(4)));
typedef short bf16x8 __attribute__((ext_vector_type(8)));

#define MFMA16(a, b, c) __builtin_amdgcn_mfma_f32_16x16x32_bf16((a), (b), (c), 0, 0, 0)
// XOR swizzle in 16B (8-short) units within a 64-short row
#define SWZ8(row, off) ((off) ^ (((row) & 7) << 3))

static __device__ __forceinline__ u16 f2bf(float f) {
  union { float f; unsigned u; } c; c.f = f;
  unsigned r = c.u + 0x7fffu + ((c.u >> 16) & 1u);
  return (u16)(r >> 16);
}

static __device__ __forceinline__ void llds16(u16* l, const u16* g) {
  __builtin_amdgcn_global_load_lds((const __attribute__((address_space(1))) void*)g,
                                   (__attribute__((address_space(3))) void*)l, 16, 0, 0);
}

// ---------------- prep: transpose weights to bf16 [N][K] ----------------
__global__ __launch_bounds__(256) void prep_weights(
    const float* __restrict__ w_qkv, const float* __restrict__ w_out,
    u16* __restrict__ wqkvT, u16* __restrict__ woutT) {
  int idx = blockIdx.x * 256 + threadIdx.x;
  if (idx < 1536 * 512) {
    int n = idx >> 9, k = idx & 511;
    wqkvT[idx] = f2bf(w_qkv[k * 1536 + n]);
  } else {
    int j = idx - 1536 * 512;
    int n = j >> 9, k = j & 511;
    woutT[j] = f2bf(w_out[k * 512 + n]);
  }
}

// ---------------- LayerNorm -> bf16 ----------------
__global__ __launch_bounds__(256) void ln_kernel(
    const float* __restrict__ x, const float* __restrict__ g,
    const float* __restrict__ be, u16* __restrict__ xn) {
  int row = blockIdx.x;
  int t = threadIdx.x;
  const float* xr = x + (size_t)row * 512;
  float2 v = *(const float2*)(xr + t * 2);
  float s = v.x + v.y, ss = v.x * v.x + v.y * v.y;
#pragma unroll
  for (int msk = 32; msk >= 1; msk >>= 1) {
    s += __shfl_xor(s, msk, 64);
    ss += __shfl_xor(ss, msk, 64);
  }
  __shared__ float red[8];
  int wv = t >> 6;
  if ((t & 63) == 0) { red[wv] = s; red[4 + wv] = ss; }
  __syncthreads();
  s = red[0] + red[1] + red[2] + red[3];
  ss = red[4] + red[5] + red[6] + red[7];
  float mu = s * (1.f / 512.f);
  float var = ss * (1.f / 512.f) - mu * mu;
  float rs = rsqrtf(var + 1e-5f);
  float a0 = (v.x - mu) * rs * g[2 * t] + be[2 * t];
  float a1 = (v.y - mu) * rs * g[2 * t + 1] + be[2 * t + 1];
  u16* o = xn + (size_t)row * 512 + t * 2;
  o[0] = f2bf(a0);
  o[1] = f2bf(a1);
}

// ---------------- QKV GEMM: [8192,512] x [512,1536], scatter q/k/vT ----------------
__global__ __launch_bounds__(256) void gemm_qkv(
    const u16* __restrict__ A, const u16* __restrict__ BT,
    u16* __restrict__ qb, u16* __restrict__ kb, u16* __restrict__ vtb) {
  __shared__ u16 lsA[128 * 64], lsB[128 * 64];
  int m0 = blockIdx.x * 128, n0 = blockIdx.y * 128;
  int tid = threadIdx.x;
  int lane = tid & 63, wave = tid >> 6;
  int wm = (wave >> 1) * 64, wn = (wave & 1) * 64;
  int lr = lane & 15, lq = lane >> 4;
  f32x4 acc[4][4] = {};
  for (int kt = 0; kt < 8; ++kt) {
#pragma unroll
    for (int c = 0; c < 4; ++c) {
      int ci = c * 256 + tid;
      int row = ci >> 3, colb = ci & 7;
      int goff = kt * 64 + ((colb * 8) ^ ((row & 7) * 8));
      llds16(&lsA[ci * 8], &A[(size_t)(m0 + row) * 512 + goff]);
      llds16(&lsB[ci * 8], &BT[(size_t)(n0 + row) * 512 + goff]);
    }
    __syncthreads();
#pragma unroll
    for (int ks = 0; ks < 2; ++ks) {
      bf16x8 af[4], bfr[4];
#pragma unroll
      for (int i = 0; i < 4; ++i) {
        int ra = wm + i * 16 + lr;
        af[i] = *(const bf16x8*)&lsA[ra * 64 + SWZ8(ra, ks * 32 + lq * 8)];
        int rb = wn + i * 16 + lr;
        bfr[i] = *(const bf16x8*)&lsB[rb * 64 + SWZ8(rb, ks * 32 + lq * 8)];
      }
#pragma unroll
      for (int i = 0; i < 4; ++i)
#pragma unroll
        for (int j = 0; j < 4; ++j)
          acc[i][j] = MFMA16(af[i], bfr[j], acc[i][j]);
    }
    __syncthreads();
  }
  // epilogue: n<512 -> q (scaled), <1024 -> k, else v transposed [B,H,D,T]
#pragma unroll
  for (int j = 0; j < 4; ++j) {
    int gn = n0 + wn + j * 16 + lr;
    int sec = gn >> 9;
    int h = (gn >> 6) & 7;
    int d = gn & 63;
#pragma unroll
    for (int i = 0; i < 4; ++i) {
      int gm = m0 + wm + i * 16 + lq * 4;
      int b = gm >> 11, t0 = gm & 2047;
      int bh = b * 8 + h;
      if (sec == 0) {
#pragma unroll
        for (int r = 0; r < 4; ++r)
          qb[((size_t)bh * 2048 + t0 + r) * 64 + d] = f2bf(acc[i][j][r] * 0.125f);
      } else if (sec == 1) {
#pragma unroll
        for (int r = 0; r < 4; ++r)
          kb[((size_t)bh * 2048 + t0 + r) * 64 + d] = f2bf(acc[i][j][r]);
      } else {
        ushort4 pk;
        pk.x = f2bf(acc[i][j][0]);
        pk.y = f2bf(acc[i][j][1]);
        pk.z = f2bf(acc[i][j][2]);
        pk.w = f2bf(acc[i][j][3]);
        *(ushort4*)&vtb[((size_t)bh * 64 + d) * 2048 + t0] = pk;
      }
    }
  }
}

// ---------------- frame-causal flash attention ----------------
__global__ __launch_bounds__(256) void attn_kernel(
    const u16* __restrict__ qb, const u16* __restrict__ kb,
    const u16* __restrict__ vtb, u16* __restrict__ ao) {
  int qf = 31 - (int)blockIdx.x;  // heavy blocks first
  int bh = blockIdx.y;
  int tid = threadIdx.x, lane = tid & 63, wave = tid >> 6;
  int lr = lane & 15, lq = lane >> 4;
  __shared__ u16 lsK[64 * 64], lsV[64 * 64];
  __shared__ u16 lsP[4][16 * 64];
  const u16* qbase = qb + ((size_t)bh * 2048 + qf * 64) * 64;
  int qrow = wave * 16 + lr;
  bf16x8 qa0 = *(const bf16x8*)&qbase[qrow * 64 + lq * 8];
  bf16x8 qa1 = *(const bf16x8*)&qbase[qrow * 64 + 32 + lq * 8];
  const u16* kfb = kb + (size_t)bh * 2048 * 64;
  const u16* vfb = vtb + (size_t)bh * 64 * 2048;
  f32x4 o[4] = {};
  float m[4], l[4];
#pragma unroll
  for (int r = 0; r < 4; ++r) { m[r] = -1e30f; l[r] = 0.f; }
  for (int kf = 0; kf <= qf; ++kf) {
    // stage K [64tok][64d] and V^T [64d][64tok] (pre-swizzled source, linear LDS)
#pragma unroll
    for (int c = 0; c < 2; ++c) {
      int ci = c * 256 + tid;
      int row = ci >> 3, colb = ci & 7;
      int sw = (colb * 8) ^ ((row & 7) * 8);
      llds16(&lsK[ci * 8], &kfb[(size_t)(kf * 64 + row) * 64 + sw]);
      llds16(&lsV[ci * 8], &vfb[(size_t)row * 2048 + kf * 64 + sw]);
    }
    __syncthreads();
    // S = Q K^T  (scale pre-folded into q)
    f32x4 s[4];
#pragma unroll
    for (int c = 0; c < 4; ++c) {
      int rk = c * 16 + lr;
      bf16x8 b0 = *(const bf16x8*)&lsK[rk * 64 + SWZ8(rk, lq * 8)];
      bf16x8 b1 = *(const bf16x8*)&lsK[rk * 64 + SWZ8(rk, 32 + lq * 8)];
      f32x4 z = {};
      z = MFMA16(qa0, b0, z);
      z = MFMA16(qa1, b1, z);
      s[c] = z;
    }
    // online softmax (rows live in 16-lane groups)
    float al[4];
#pragma unroll
    for (int r = 0; r < 4; ++r) {
      float v = fmaxf(fmaxf(s[0][r], s[1][r]), fmaxf(s[2][r], s[3][r]));
      v = fmaxf(v, __shfl_xor(v, 1, 16));
      v = fmaxf(v, __shfl_xor(v, 2, 16));
      v = fmaxf(v, __shfl_xor(v, 4, 16));
      v = fmaxf(v, __shfl_xor(v, 8, 16));
      float mn = fmaxf(m[r], v);
      al[r] = __expf(m[r] - mn);
      m[r] = mn;
    }
#pragma unroll
    for (int c = 0; c < 4; ++c)
#pragma unroll
      for (int r = 0; r < 4; ++r)
        s[c][r] = __expf(s[c][r] - m[r]);
#pragma unroll
    for (int r = 0; r < 4; ++r) {
      float v = s[0][r] + s[1][r] + s[2][r] + s[3][r];
      v += __shfl_xor(v, 1, 16);
      v += __shfl_xor(v, 2, 16);
      v += __shfl_xor(v, 4, 16);
      v += __shfl_xor(v, 8, 16);
      l[r] = l[r] * al[r] + v;
    }
#pragma unroll
    for (int oc = 0; oc < 4; ++oc)
#pragma unroll
      for (int r = 0; r < 4; ++r)
        o[oc][r] *= al[r];
    // P -> bf16 via wave-private swizzled LDS
    u16* pw = lsP[wave];
#pragma unroll
    for (int c = 0; c < 4; ++c)
#pragma unroll
      for (int r = 0; r < 4; ++r) {
        int q = lq * 4 + r;
        pw[q * 64 + ((c * 16 + lr) ^ ((q & 7) << 3))] = f2bf(s[c][r]);
      }
    bf16x8 pa0 = *(const bf16x8*)&pw[lr * 64 + SWZ8(lr, lq * 8)];
    bf16x8 pa1 = *(const bf16x8*)&pw[lr * 64 + SWZ8(lr, 32 + lq * 8)];
    // O += P V
#pragma unroll
    for (int oc = 0; oc < 4; ++oc) {
      int rv = oc * 16 + lr;
      bf16x8 v0 = *(const bf16x8*)&lsV[rv * 64 + SWZ8(rv, lq * 8)];
      bf16x8 v1 = *(const bf16x8*)&lsV[rv * 64 + SWZ8(rv, 32 + lq * 8)];
      o[oc] = MFMA16(pa0, v0, o[oc]);
      o[oc] = MFMA16(pa1, v1, o[oc]);
    }
    __syncthreads();
  }
  int b = bh >> 3, h = bh & 7;
#pragma unroll
  for (int oc = 0; oc < 4; ++oc) {
#pragma unroll
    for (int r = 0; r < 4; ++r) {
      int q = qf * 64 + wave * 16 + lq * 4 + r;
      int col = h * 64 + oc * 16 + lr;
      ao[((size_t)b * 2048 + q) * 512 + col] = f2bf(o[oc][r] / l[r]);
    }
  }
}

// ---------------- out GEMM: [8192,512] x [512,512] + bias -> fp32 ----------------
__global__ __launch_bounds__(256) void gemm_out(
    const u16* __restrict__ A, const u16* __restrict__ BT,
    const float* __restrict__ bias, float* __restrict__ out) {
  __shared__ u16 lsA[128 * 64], lsB[128 * 64];
  int m0 = blockIdx.x * 128, n0 = blockIdx.y * 128;
  int tid = threadIdx.x;
  int lane = tid & 63, wave = tid >> 6;
  int wm = (wave >> 1) * 64, wn = (wave & 1) * 64;
  int lr = lane & 15, lq = lane >> 4;
  f32x4 acc[4][4] = {};
  for (int kt = 0; kt < 8; ++kt) {
#pragma unroll
    for (int c = 0; c < 4; ++c) {
      int ci = c * 256 + tid;
      int row = ci >> 3, colb = ci & 7;
      int goff = kt * 64 + ((colb * 8) ^ ((row & 7) * 8));
      llds16(&lsA[ci * 8], &A[(size_t)(m0 + row) * 512 + goff]);
      llds16(&lsB[ci * 8], &BT[(size_t)(n0 + row) * 512 + goff]);
    }
    __syncthreads();
#pragma unroll
    for (int ks = 0; ks < 2; ++ks) {
      bf16x8 af[4], bfr[4];
#pragma unroll
      for (int i = 0; i < 4; ++i) {
        int ra = wm + i * 16 + lr;
        af[i] = *(const bf16x8*)&lsA[ra * 64 + SWZ8(ra, ks * 32 + lq * 8)];
        int rb = wn + i * 16 + lr;
        bfr[i] = *(const bf16x8*)&lsB[rb * 64 + SWZ8(rb, ks * 32 + lq * 8)];
      }
#pragma unroll
      for (int i = 0; i < 4; ++i)
#pragma unroll
        for (int j = 0; j < 4; ++j)
          acc[i][j] = MFMA16(af[i], bfr[j], acc[i][j]);
    }
    __syncthreads();
  }
#pragma unroll
  for (int j = 0; j < 4; ++j) {
    int gn = n0 + wn + j * 16 + lr;
    float bj = bias[gn];
#pragma unroll
    for (int i = 0; i < 4; ++i) {
      int gm = m0 + wm + i * 16 + lq * 4;
#pragma unroll
      for (int r = 0; r < 4; ++r)
        out[(size_t)(gm + r) * 512 + gn] = acc[i][j][r] + bj;
    }
  }
}

extern "C" void kernel_launch(void* const* d_in, const int* in_sizes, int n_in,
                              void* d_out, int out_size, void* d_ws, size_t ws_size,
                              hipStream_t stream) {
  const float* x = (const float*)d_in[0];
  const float* ln_g = (const float*)d_in[1];
  const float* ln_b = (const float*)d_in[2];
  const float* w_qkv = (const float*)d_in[3];
  const float* w_out = (const float*)d_in[4];
  const float* b_out = (const float*)d_in[5];
  float* out = (float*)d_out;
  char* ws = (char*)d_ws;

  u16* xn    = (u16*)(ws + 0);          //  8 MB  [8192][512] bf16
  u16* wqkvT = (u16*)(ws + 8388608);    //  1.5 MB [1536][512]
  u16* woutT = (u16*)(ws + 9961472);    //  0.5 MB [512][512]
  u16* qb    = (u16*)(ws + 10485760);   //  8 MB  [B,H,T,D]
  u16* kb    = (u16*)(ws + 18874368);   //  8 MB  [B,H,T,D]
  u16* vtb   = (u16*)(ws + 27262976);   //  8 MB  [B,H,D,T]
  u16* ao    = (u16*)(ws + 35651584);   //  8 MB  [8192][512]

  prep_weights<<<4096, 256, 0, stream>>>(w_qkv, w_out, wqkvT, woutT);
  ln_kernel<<<8192, 256, 0, stream>>>(x, ln_g, ln_b, xn);
  gemm_qkv<<<dim3(64, 12), 256, 0, stream>>>(xn, wqkvT, qb, kb, vtb);
  attn_kernel<<<dim3(32, 32), 256, 0, stream>>>(qb, kb, vtb, ao);
  gemm_out<<<dim3(64, 4), 256, 0, stream>>>(ao, woutT, b_out, out);
}

// Round 2
// 187.233 us; speedup vs baseline: 1.2458x; 1.2458x over previous
//
#include <hip/hip_runtime.h>

typedef unsigned short u16;
typedef float f32x4 __attribute__((ext_vector_type(4)));
typedef short bf16x8 __attribute__((ext_vector_type(8)));

#define MFMA16(a, b, c) __builtin_amdgcn_mfma_f32_16x16x32_bf16((a), (b), (c), 0, 0, 0)
// XOR swizzle in 16B (8-short) units within a 64-short row
#define SWZ8(row, off) ((off) ^ (((row) & 7) << 3))

#define CFENCE() asm volatile("" ::: "memory")
#define BARRIER() do { CFENCE(); __builtin_amdgcn_s_barrier(); CFENCE(); } while (0)
#define VMW(n) asm volatile("s_waitcnt vmcnt(" #n ")" ::: "memory")

static __device__ __forceinline__ u16 f2bf(float f) {
  union { float f; unsigned u; } c; c.f = f;
  unsigned r = c.u + 0x7fffu + ((c.u >> 16) & 1u);
  return (u16)(r >> 16);
}

static __device__ __forceinline__ void llds16(u16* l, const u16* g) {
  __builtin_amdgcn_global_load_lds((const __attribute__((address_space(1))) void*)g,
                                   (__attribute__((address_space(3))) void*)l, 16, 0, 0);
}

// ---------------- prep: transpose weights to bf16 [N][K] ----------------
__global__ __launch_bounds__(256) void prep_weights(
    const float* __restrict__ w_qkv, const float* __restrict__ w_out,
    u16* __restrict__ wqkvT, u16* __restrict__ woutT) {
  int idx = blockIdx.x * 256 + threadIdx.x;
  if (idx < 1536 * 512) {
    int n = idx >> 9, k = idx & 511;
    wqkvT[idx] = f2bf(w_qkv[k * 1536 + n]);
  } else {
    int j = idx - 1536 * 512;
    int n = j >> 9, k = j & 511;
    woutT[j] = f2bf(w_out[k * 512 + n]);
  }
}

// ---------------- LayerNorm -> bf16 ----------------
__global__ __launch_bounds__(256) void ln_kernel(
    const float* __restrict__ x, const float* __restrict__ g,
    const float* __restrict__ be, u16* __restrict__ xn) {
  int row = blockIdx.x;
  int t = threadIdx.x;
  const float* xr = x + (size_t)row * 512;
  float2 v = *(const float2*)(xr + t * 2);
  float s = v.x + v.y, ss = v.x * v.x + v.y * v.y;
#pragma unroll
  for (int msk = 32; msk >= 1; msk >>= 1) {
    s += __shfl_xor(s, msk, 64);
    ss += __shfl_xor(ss, msk, 64);
  }
  __shared__ float red[8];
  int wv = t >> 6;
  if ((t & 63) == 0) { red[wv] = s; red[4 + wv] = ss; }
  __syncthreads();
  s = red[0] + red[1] + red[2] + red[3];
  ss = red[4] + red[5] + red[6] + red[7];
  float mu = s * (1.f / 512.f);
  float var = ss * (1.f / 512.f) - mu * mu;
  float rs = rsqrtf(var + 1e-5f);
  float a0 = (v.x - mu) * rs * g[2 * t] + be[2 * t];
  float a1 = (v.y - mu) * rs * g[2 * t + 1] + be[2 * t + 1];
  u16* o = xn + (size_t)row * 512 + t * 2;
  o[0] = f2bf(a0);
  o[1] = f2bf(a1);
}

// ---------------- QKV GEMM: [8192,512] x [512,1536], scatter q/k/vT ----------------
__global__ __launch_bounds__(256) void gemm_qkv(
    const u16* __restrict__ A, const u16* __restrict__ BT,
    u16* __restrict__ qb, u16* __restrict__ kb, u16* __restrict__ vtb) {
  __shared__ u16 lsA[128 * 64], lsB[128 * 64];
  int m0 = blockIdx.x * 128, n0 = blockIdx.y * 128;
  int tid = threadIdx.x;
  int lane = tid & 63, wave = tid >> 6;
  int wm = (wave >> 1) * 64, wn = (wave & 1) * 64;
  int lr = lane & 15, lq = lane >> 4;
  f32x4 acc[4][4] = {};
  for (int kt = 0; kt < 8; ++kt) {
#pragma unroll
    for (int c = 0; c < 4; ++c) {
      int ci = c * 256 + tid;
      int row = ci >> 3, colb = ci & 7;
      int goff = kt * 64 + ((colb * 8) ^ ((row & 7) * 8));
      llds16(&lsA[ci * 8], &A[(size_t)(m0 + row) * 512 + goff]);
      llds16(&lsB[ci * 8], &BT[(size_t)(n0 + row) * 512 + goff]);
    }
    __syncthreads();
#pragma unroll
    for (int ks = 0; ks < 2; ++ks) {
      bf16x8 af[4], bfr[4];
#pragma unroll
      for (int i = 0; i < 4; ++i) {
        int ra = wm + i * 16 + lr;
        af[i] = *(const bf16x8*)&lsA[ra * 64 + SWZ8(ra, ks * 32 + lq * 8)];
        int rb = wn + i * 16 + lr;
        bfr[i] = *(const bf16x8*)&lsB[rb * 64 + SWZ8(rb, ks * 32 + lq * 8)];
      }
#pragma unroll
      for (int i = 0; i < 4; ++i)
#pragma unroll
        for (int j = 0; j < 4; ++j)
          acc[i][j] = MFMA16(af[i], bfr[j], acc[i][j]);
    }
    __syncthreads();
  }
  // epilogue: n<512 -> q (scaled), <1024 -> k, else v transposed [B,H,D,T]
#pragma unroll
  for (int j = 0; j < 4; ++j) {
    int gn = n0 + wn + j * 16 + lr;
    int sec = gn >> 9;
    int h = (gn >> 6) & 7;
    int d = gn & 63;
#pragma unroll
    for (int i = 0; i < 4; ++i) {
      int gm = m0 + wm + i * 16 + lq * 4;
      int b = gm >> 11, t0 = gm & 2047;
      int bh = b * 8 + h;
      if (sec == 0) {
#pragma unroll
        for (int r = 0; r < 4; ++r)
          qb[((size_t)bh * 2048 + t0 + r) * 64 + d] = f2bf(acc[i][j][r] * 0.125f);
      } else if (sec == 1) {
#pragma unroll
        for (int r = 0; r < 4; ++r)
          kb[((size_t)bh * 2048 + t0 + r) * 64 + d] = f2bf(acc[i][j][r]);
      } else {
        ushort4 pk;
        pk.x = f2bf(acc[i][j][0]);
        pk.y = f2bf(acc[i][j][1]);
        pk.z = f2bf(acc[i][j][2]);
        pk.w = f2bf(acc[i][j][3]);
        *(ushort4*)&vtb[((size_t)bh * 64 + d) * 2048 + t0] = pk;
      }
    }
  }
}

// ---------------- frame-causal flash attention (double-buffered) ----------------
__global__ __launch_bounds__(256) void attn_kernel(
    const u16* __restrict__ qb, const u16* __restrict__ kb,
    const u16* __restrict__ vtb, u16* __restrict__ ao) {
  // XCD-aware flattening: dispatch index i -> XCD i%8 (round-robin heuristic).
  // Each XCD owns 4 bh values -> its K/V/Q working set (~3MB) fits its 4MB L2.
  int blk = blockIdx.x;
  int xcd = blk & 7;
  int seq = blk >> 3;            // 0..127
  int bh = xcd * 4 + (seq & 3);  // 4 bh per XCD
  int qf = 31 - (seq >> 2);      // heavy frames first
  int tid = threadIdx.x, lane = tid & 63, wave = tid >> 6;
  int lr = lane & 15, lq = lane >> 4;
  __shared__ u16 lsK[2][64 * 64], lsV[2][64 * 64];
  __shared__ u16 lsP[4][16 * 64];
  const u16* kfb = kb + (size_t)bh * 2048 * 64;
  const u16* vfb = vtb + (size_t)bh * 64 * 2048;

  // staging geometry: 256 threads x 2 chunks x 16B per buffer (K and V)
  int ci0 = tid, ci1 = 256 + tid;
  int r0 = ci0 >> 3, cb0 = ci0 & 7, sw0 = (cb0 * 8) ^ ((r0 & 7) * 8);
  int r1 = ci1 >> 3, cb1 = ci1 & 7, sw1 = (cb1 * 8) ^ ((r1 & 7) * 8);

#define STAGE(buf, kf_)                                                        \
  do {                                                                         \
    const u16* kp = kfb + (size_t)(kf_) * 64 * 64;                             \
    llds16(&lsK[buf][ci0 * 8], &kp[(size_t)r0 * 64 + sw0]);                    \
    llds16(&lsK[buf][ci1 * 8], &kp[(size_t)r1 * 64 + sw1]);                    \
    llds16(&lsV[buf][ci0 * 8], &vfb[(size_t)r0 * 2048 + (kf_) * 64 + sw0]);    \
    llds16(&lsV[buf][ci1 * 8], &vfb[(size_t)r1 * 2048 + (kf_) * 64 + sw1]);    \
  } while (0)

  STAGE(0, 0);

  const u16* qbase = qb + ((size_t)bh * 2048 + qf * 64) * 64;
  int qrow = wave * 16 + lr;
  bf16x8 qa0 = *(const bf16x8*)&qbase[qrow * 64 + lq * 8];
  bf16x8 qa1 = *(const bf16x8*)&qbase[qrow * 64 + 32 + lq * 8];

  f32x4 o[4] = {};
  float m[4], l[4];
#pragma unroll
  for (int r = 0; r < 4; ++r) { m[r] = -1e30f; l[r] = 0.f; }

  for (int kf = 0; kf <= qf; ++kf) {
    int cur = kf & 1;
    if (kf < qf) {
      STAGE(cur ^ 1, kf + 1);
      VMW(4);  // my 4 loads for buf[cur] complete; next tile's stay in flight
    } else {
      VMW(0);
    }
    BARRIER();  // all waves' buf[cur] staging landed
    // S = Q K^T  (scale pre-folded into q)
    f32x4 s[4];
#pragma unroll
    for (int c = 0; c < 4; ++c) {
      int rk = c * 16 + lr;
      bf16x8 b0 = *(const bf16x8*)&lsK[cur][rk * 64 + SWZ8(rk, lq * 8)];
      bf16x8 b1 = *(const bf16x8*)&lsK[cur][rk * 64 + SWZ8(rk, 32 + lq * 8)];
      f32x4 z = {};
      z = MFMA16(qa0, b0, z);
      z = MFMA16(qa1, b1, z);
      s[c] = z;
    }
    // online softmax (rows live in 16-lane groups)
    float al[4];
#pragma unroll
    for (int r = 0; r < 4; ++r) {
      float v = fmaxf(fmaxf(s[0][r], s[1][r]), fmaxf(s[2][r], s[3][r]));
      v = fmaxf(v, __shfl_xor(v, 1, 16));
      v = fmaxf(v, __shfl_xor(v, 2, 16));
      v = fmaxf(v, __shfl_xor(v, 4, 16));
      v = fmaxf(v, __shfl_xor(v, 8, 16));
      float mn = fmaxf(m[r], v);
      al[r] = __expf(m[r] - mn);
      m[r] = mn;
    }
#pragma unroll
    for (int c = 0; c < 4; ++c)
#pragma unroll
      for (int r = 0; r < 4; ++r)
        s[c][r] = __expf(s[c][r] - m[r]);
#pragma unroll
    for (int r = 0; r < 4; ++r) {
      float v = s[0][r] + s[1][r] + s[2][r] + s[3][r];
      v += __shfl_xor(v, 1, 16);
      v += __shfl_xor(v, 2, 16);
      v += __shfl_xor(v, 4, 16);
      v += __shfl_xor(v, 8, 16);
      l[r] = l[r] * al[r] + v;
    }
#pragma unroll
    for (int oc = 0; oc < 4; ++oc)
#pragma unroll
      for (int r = 0; r < 4; ++r)
        o[oc][r] *= al[r];
    // P -> bf16 via wave-private swizzled LDS
    u16* pw = lsP[wave];
#pragma unroll
    for (int c = 0; c < 4; ++c)
#pragma unroll
      for (int r = 0; r < 4; ++r) {
        int q = lq * 4 + r;
        pw[q * 64 + ((c * 16 + lr) ^ ((q & 7) << 3))] = f2bf(s[c][r]);
      }
    bf16x8 pa0 = *(const bf16x8*)&pw[lr * 64 + SWZ8(lr, lq * 8)];
    bf16x8 pa1 = *(const bf16x8*)&pw[lr * 64 + SWZ8(lr, 32 + lq * 8)];
    // O += P V
#pragma unroll
    for (int oc = 0; oc < 4; ++oc) {
      int rv = oc * 16 + lr;
      bf16x8 v0 = *(const bf16x8*)&lsV[cur][rv * 64 + SWZ8(rv, lq * 8)];
      bf16x8 v1 = *(const bf16x8*)&lsV[cur][rv * 64 + SWZ8(rv, 32 + lq * 8)];
      o[oc] = MFMA16(pa0, v0, o[oc]);
      o[oc] = MFMA16(pa1, v1, o[oc]);
    }
    BARRIER();  // all reads of buf[cur] done before it is restaged
  }
#undef STAGE
  int b = bh >> 3, h = bh & 7;
#pragma unroll
  for (int oc = 0; oc < 4; ++oc) {
#pragma unroll
    for (int r = 0; r < 4; ++r) {
      int q = qf * 64 + wave * 16 + lq * 4 + r;
      int col = h * 64 + oc * 16 + lr;
      ao[((size_t)b * 2048 + q) * 512 + col] = f2bf(o[oc][r] / l[r]);
    }
  }
}

// ---------------- out GEMM: [8192,512] x [512,512] + bias -> fp32 ----------------
__global__ __launch_bounds__(256) void gemm_out(
    const u16* __restrict__ A, const u16* __restrict__ BT,
    const float* __restrict__ bias, float* __restrict__ out) {
  __shared__ u16 lsA[128 * 64], lsB[128 * 64];
  int m0 = blockIdx.x * 128, n0 = blockIdx.y * 128;
  int tid = threadIdx.x;
  int lane = tid & 63, wave = tid >> 6;
  int wm = (wave >> 1) * 64, wn = (wave & 1) * 64;
  int lr = lane & 15, lq = lane >> 4;
  f32x4 acc[4][4] = {};
  for (int kt = 0; kt < 8; ++kt) {
#pragma unroll
    for (int c = 0; c < 4; ++c) {
      int ci = c * 256 + tid;
      int row = ci >> 3, colb = ci & 7;
      int goff = kt * 64 + ((colb * 8) ^ ((row & 7) * 8));
      llds16(&lsA[ci * 8], &A[(size_t)(m0 + row) * 512 + goff]);
      llds16(&lsB[ci * 8], &BT[(size_t)(n0 + row) * 512 + goff]);
    }
    __syncthreads();
#pragma unroll
    for (int ks = 0; ks < 2; ++ks) {
      bf16x8 af[4], bfr[4];
#pragma unroll
      for (int i = 0; i < 4; ++i) {
        int ra = wm + i * 16 + lr;
        af[i] = *(const bf16x8*)&lsA[ra * 64 + SWZ8(ra, ks * 32 + lq * 8)];
        int rb = wn + i * 16 + lr;
        bfr[i] = *(const bf16x8*)&lsB[rb * 64 + SWZ8(rb, ks * 32 + lq * 8)];
      }
#pragma unroll
      for (int i = 0; i < 4; ++i)
#pragma unroll
        for (int j = 0; j < 4; ++j)
          acc[i][j] = MFMA16(af[i], bfr[j], acc[i][j]);
    }
    __syncthreads();
  }
#pragma unroll
  for (int j = 0; j < 4; ++j) {
    int gn = n0 + wn + j * 16 + lr;
    float bj = bias[gn];
#pragma unroll
    for (int i = 0; i < 4; ++i) {
      int gm = m0 + wm + i * 16 + lq * 4;
#pragma unroll
      for (int r = 0; r < 4; ++r)
        out[(size_t)(gm + r) * 512 + gn] = acc[i][j][r] + bj;
    }
  }
}

extern "C" void kernel_launch(void* const* d_in, const int* in_sizes, int n_in,
                              void* d_out, int out_size, void* d_ws, size_t ws_size,
                              hipStream_t stream) {
  const float* x = (const float*)d_in[0];
  const float* ln_g = (const float*)d_in[1];
  const float* ln_b = (const float*)d_in[2];
  const float* w_qkv = (const float*)d_in[3];
  const float* w_out = (const float*)d_in[4];
  const float* b_out = (const float*)d_in[5];
  float* out = (float*)d_out;
  char* ws = (char*)d_ws;

  u16* xn    = (u16*)(ws + 0);          //  8 MB  [8192][512] bf16
  u16* wqkvT = (u16*)(ws + 8388608);    //  1.5 MB [1536][512]
  u16* woutT = (u16*)(ws + 9961472);    //  0.5 MB [512][512]
  u16* qb    = (u16*)(ws + 10485760);   //  8 MB  [B,H,T,D]
  u16* kb    = (u16*)(ws + 18874368);   //  8 MB  [B,H,T,D]
  u16* vtb   = (u16*)(ws + 27262976);   //  8 MB  [B,H,D,T]
  u16* ao    = (u16*)(ws + 35651584);   //  8 MB  [8192][512]

  prep_weights<<<4096, 256, 0, stream>>>(w_qkv, w_out, wqkvT, woutT);
  ln_kernel<<<8192, 256, 0, stream>>>(x, ln_g, ln_b, xn);
  gemm_qkv<<<dim3(64, 12), 256, 0, stream>>>(xn, wqkvT, qb, kb, vtb);
  attn_kernel<<<1024, 256, 0, stream>>>(qb, kb, vtb, ao);
  gemm_out<<<dim3(64, 4), 256, 0, stream>>>(ao, woutT, b_out, out);
}

// Round 5
// 169.831 us; speedup vs baseline: 1.3735x; 1.1025x over previous
//
#include <hip/hip_runtime.h>

typedef unsigned short u16;
typedef float f32x4 __attribute__((ext_vector_type(4)));
typedef short bf16x8 __attribute__((ext_vector_type(8)));

#define MFMA16(a, b, c) __builtin_amdgcn_mfma_f32_16x16x32_bf16((a), (b), (c), 0, 0, 0)
// XOR swizzle in 16B (8-short) units within a 64-short row
#define SWZ8(row, off) ((off) ^ (((row) & 7) << 3))

#define CFENCE() asm volatile("" ::: "memory")
#define BARRIER() do { CFENCE(); __builtin_amdgcn_s_barrier(); CFENCE(); } while (0)
#define VMW(n) asm volatile("s_waitcnt vmcnt(" #n ")" ::: "memory")

// round-to-nearest-even f32 -> bf16 (software; proven rounds 0-2)
static __device__ __forceinline__ u16 f2bf(float f) {
  union { float f; unsigned u; } c; c.f = f;
  unsigned r = c.u + 0x7fffu + ((c.u >> 16) & 1u);
  return (u16)(r >> 16);
}

static __device__ __forceinline__ void llds16(u16* l, const u16* g) {
  __builtin_amdgcn_global_load_lds((const __attribute__((address_space(1))) void*)g,
                                   (__attribute__((address_space(3))) void*)l, 16, 0, 0);
}

// ---------------- prep: transpose weights to bf16 [N][K] ----------------
__global__ __launch_bounds__(256) void prep_weights(
    const float* __restrict__ w_qkv, const float* __restrict__ w_out,
    u16* __restrict__ wqkvT, u16* __restrict__ woutT) {
  int idx = blockIdx.x * 256 + threadIdx.x;
  if (idx < 1536 * 512) {
    int n = idx >> 9, k = idx & 511;
    wqkvT[idx] = f2bf(w_qkv[k * 1536 + n]);
  } else {
    int j = idx - 1536 * 512;
    int n = j >> 9, k = j & 511;
    woutT[j] = f2bf(w_out[k * 512 + n]);
  }
}

// ---------------- LayerNorm -> bf16 (block per row; proven rounds 0-2) ----------------
__global__ __launch_bounds__(256) void ln_kernel(
    const float* __restrict__ x, const float* __restrict__ g,
    const float* __restrict__ be, u16* __restrict__ xn) {
  int row = blockIdx.x;
  int t = threadIdx.x;
  const float* xr = x + (size_t)row * 512;
  float2 v = *(const float2*)(xr + t * 2);
  float s = v.x + v.y, ss = v.x * v.x + v.y * v.y;
#pragma unroll
  for (int msk = 32; msk >= 1; msk >>= 1) {
    s += __shfl_xor(s, msk, 64);
    ss += __shfl_xor(ss, msk, 64);
  }
  __shared__ float red[8];
  int wv = t >> 6;
  if ((t & 63) == 0) { red[wv] = s; red[4 + wv] = ss; }
  __syncthreads();
  s = red[0] + red[1] + red[2] + red[3];
  ss = red[4] + red[5] + red[6] + red[7];
  float mu = s * (1.f / 512.f);
  float var = ss * (1.f / 512.f) - mu * mu;
  float rs = rsqrtf(var + 1e-5f);
  float a0 = (v.x - mu) * rs * g[2 * t] + be[2 * t];
  float a1 = (v.y - mu) * rs * g[2 * t + 1] + be[2 * t + 1];
  u16* o = xn + (size_t)row * 512 + t * 2;
  o[0] = f2bf(a0);
  o[1] = f2bf(a1);
}

// ---------------- QKV GEMM: [8192,512] x [512,1536], scatter q/k/vT ----------------
__global__ __launch_bounds__(256) void gemm_qkv(
    const u16* __restrict__ A, const u16* __restrict__ BT,
    u16* __restrict__ qb, u16* __restrict__ kb, u16* __restrict__ vtb) {
  __shared__ u16 lsA[128 * 64], lsB[128 * 64];
  int m0 = blockIdx.x * 128, n0 = blockIdx.y * 128;
  int tid = threadIdx.x;
  int lane = tid & 63, wave = tid >> 6;
  int wm = (wave >> 1) * 64, wn = (wave & 1) * 64;
  int lr = lane & 15, lq = lane >> 4;
  f32x4 acc[4][4] = {};
  for (int kt = 0; kt < 8; ++kt) {
#pragma unroll
    for (int c = 0; c < 4; ++c) {
      int ci = c * 256 + tid;
      int row = ci >> 3, colb = ci & 7;
      int goff = kt * 64 + ((colb * 8) ^ ((row & 7) * 8));
      llds16(&lsA[ci * 8], &A[(size_t)(m0 + row) * 512 + goff]);
      llds16(&lsB[ci * 8], &BT[(size_t)(n0 + row) * 512 + goff]);
    }
    __syncthreads();
#pragma unroll
    for (int ks = 0; ks < 2; ++ks) {
      bf16x8 af[4], bfr[4];
#pragma unroll
      for (int i = 0; i < 4; ++i) {
        int ra = wm + i * 16 + lr;
        af[i] = *(const bf16x8*)&lsA[ra * 64 + SWZ8(ra, ks * 32 + lq * 8)];
        int rb = wn + i * 16 + lr;
        bfr[i] = *(const bf16x8*)&lsB[rb * 64 + SWZ8(rb, ks * 32 + lq * 8)];
      }
#pragma unroll
      for (int i = 0; i < 4; ++i)
#pragma unroll
        for (int j = 0; j < 4; ++j)
          acc[i][j] = MFMA16(af[i], bfr[j], acc[i][j]);
    }
    __syncthreads();
  }
  // epilogue: n<512 -> q (scaled), <1024 -> k, else v transposed [B,H,D,T]
#pragma unroll
  for (int j = 0; j < 4; ++j) {
    int gn = n0 + wn + j * 16 + lr;
    int sec = gn >> 9;
    int h = (gn >> 6) & 7;
    int d = gn & 63;
#pragma unroll
    for (int i = 0; i < 4; ++i) {
      int gm = m0 + wm + i * 16 + lq * 4;
      int b = gm >> 11, t0 = gm & 2047;
      int bh = b * 8 + h;
      if (sec == 0) {
#pragma unroll
        for (int r = 0; r < 4; ++r)
          qb[((size_t)bh * 2048 + t0 + r) * 64 + d] = f2bf(acc[i][j][r] * 0.125f);
      } else if (sec == 1) {
#pragma unroll
        for (int r = 0; r < 4; ++r)
          kb[((size_t)bh * 2048 + t0 + r) * 64 + d] = f2bf(acc[i][j][r]);
      } else {
        ushort4 pk;
        pk.x = f2bf(acc[i][j][0]);
        pk.y = f2bf(acc[i][j][1]);
        pk.z = f2bf(acc[i][j][2]);
        pk.w = f2bf(acc[i][j][3]);
        *(ushort4*)&vtb[((size_t)bh * 64 + d) * 2048 + t0] = pk;
      }
    }
  }
}

// ---------------- frame-causal flash attention (hybrid) ----------------
// Swapped QK^T: S^T = mfma(K,Q) -> lane-local softmax for q = lane&15
// (15 fmax + 16 exp in-lane + 2+2 shuffles). P then goes through the
// round-2-PROVEN LDS path (packed 8B writes) and PV/epilogue are round-2
// verbatim 16x16x32 MFMA. al and 1/l redistributed to output rows by shfl.
__global__ __launch_bounds__(256) void attn_kernel(
    const u16* __restrict__ qb, const u16* __restrict__ kb,
    const u16* __restrict__ vtb, u16* __restrict__ ao) {
  int blk = blockIdx.x;
  int xcd = blk & 7;
  int seq = blk >> 3;            // 0..127
  int bh = xcd * 4 + (seq & 3);  // 4 bh per XCD -> L2-resident K/V
  int qf = 31 - (seq >> 2);      // heavy frames first
  int tid = threadIdx.x, lane = tid & 63, wave = tid >> 6;
  int lr = lane & 15, lq = lane >> 4;
  __shared__ u16 lsK[2][64 * 64], lsV[2][64 * 64];
  __shared__ u16 lsP[4][16 * 64];
  const u16* kfb = kb + (size_t)bh * 2048 * 64;
  const u16* vfb = vtb + (size_t)bh * 64 * 2048;

  int ci0 = tid, ci1 = 256 + tid;
  int r0 = ci0 >> 3, cb0 = ci0 & 7, sw0 = (cb0 * 8) ^ ((r0 & 7) * 8);
  int r1 = ci1 >> 3, cb1 = ci1 & 7, sw1 = (cb1 * 8) ^ ((r1 & 7) * 8);

#define STAGE(buf, kf_)                                                        \
  do {                                                                         \
    const u16* kp = kfb + (size_t)(kf_) * 64 * 64;                             \
    llds16(&lsK[buf][ci0 * 8], &kp[(size_t)r0 * 64 + sw0]);                    \
    llds16(&lsK[buf][ci1 * 8], &kp[(size_t)r1 * 64 + sw1]);                    \
    llds16(&lsV[buf][ci0 * 8], &vfb[(size_t)r0 * 2048 + (kf_) * 64 + sw0]);    \
    llds16(&lsV[buf][ci1 * 8], &vfb[(size_t)r1 * 2048 + (kf_) * 64 + sw1]);    \
  } while (0)

  STAGE(0, 0);

  const u16* qbase = qb + ((size_t)bh * 2048 + qf * 64) * 64;
  int qrow = wave * 16 + lr;
  bf16x8 qa0 = *(const bf16x8*)&qbase[qrow * 64 + lq * 8];
  bf16x8 qa1 = *(const bf16x8*)&qbase[qrow * 64 + 32 + lq * 8];

  f32x4 o[4] = {};
  float m = -1e30f, l = 0.f;

  for (int kf = 0; kf <= qf; ++kf) {
    int cur = kf & 1;
    if (kf < qf) {
      STAGE(cur ^ 1, kf + 1);
      VMW(4);  // my 4 loads for buf[cur] complete; next tile's stay in flight
    } else {
      VMW(0);
    }
    BARRIER();
    // S^T[k][q] = K.Q^T : lane holds k = 16c + 4*lq + r for its q = lr
    f32x4 s[4];
    __builtin_amdgcn_s_setprio(1);
#pragma unroll
    for (int c = 0; c < 4; ++c) {
      int rk = c * 16 + lr;
      bf16x8 k0 = *(const bf16x8*)&lsK[cur][rk * 64 + SWZ8(rk, lq * 8)];
      bf16x8 k1 = *(const bf16x8*)&lsK[cur][rk * 64 + SWZ8(rk, 32 + lq * 8)];
      f32x4 z = {};
      z = MFMA16(k0, qa0, z);
      z = MFMA16(k1, qa1, z);
      s[c] = z;
    }
    __builtin_amdgcn_s_setprio(0);
    // in-lane softmax for q = lr
    float m0 = fmaxf(fmaxf(s[0][0], s[0][1]), fmaxf(s[0][2], s[0][3]));
    float m1 = fmaxf(fmaxf(s[1][0], s[1][1]), fmaxf(s[1][2], s[1][3]));
    float m2 = fmaxf(fmaxf(s[2][0], s[2][1]), fmaxf(s[2][2], s[2][3]));
    float m3 = fmaxf(fmaxf(s[3][0], s[3][1]), fmaxf(s[3][2], s[3][3]));
    float mx = fmaxf(fmaxf(m0, m1), fmaxf(m2, m3));
    mx = fmaxf(mx, __shfl_xor(mx, 16, 64));
    mx = fmaxf(mx, __shfl_xor(mx, 32, 64));
    float mn = fmaxf(m, mx);
    float al = __expf(m - mn);
    m = mn;
    float sum = 0.f;
#pragma unroll
    for (int c = 0; c < 4; ++c) {
#pragma unroll
      for (int r = 0; r < 4; ++r) {
        s[c][r] = __expf(s[c][r] - mn);
        sum += s[c][r];
      }
    }
    sum += __shfl_xor(sum, 16, 64);
    sum += __shfl_xor(sum, 32, 64);
    l = l * al + sum;
    // redistribute al to this lane's OUTPUT rows q = 4*lq + r (held at lane q)
    float al0 = __shfl(al, lq * 4 + 0, 64);
    float al1 = __shfl(al, lq * 4 + 1, 64);
    float al2 = __shfl(al, lq * 4 + 2, 64);
    float al3 = __shfl(al, lq * 4 + 3, 64);
#pragma unroll
    for (int oc = 0; oc < 4; ++oc) {
      o[oc][0] *= al0;
      o[oc][1] *= al1;
      o[oc][2] *= al2;
      o[oc][3] *= al3;
    }
    // P -> wave-private swizzled LDS (round-2 layout), packed 8B writes:
    // lane's 4 values for k = 16c+4lq+{0..3} are contiguous in row q = lr
    u16* pw = lsP[wave];
#pragma unroll
    for (int c = 0; c < 4; ++c) {
      union { u16 h[4]; uint2 q2; } pk;
      pk.h[0] = f2bf(s[c][0]);
      pk.h[1] = f2bf(s[c][1]);
      pk.h[2] = f2bf(s[c][2]);
      pk.h[3] = f2bf(s[c][3]);
      int kbase = c * 16 + lq * 4;
      *(uint2*)&pw[lr * 64 + (kbase ^ ((lr & 7) * 8))] = pk.q2;
    }
    // read back as A-fragment (round-2 verbatim)
    bf16x8 pa0 = *(const bf16x8*)&pw[lr * 64 + SWZ8(lr, lq * 8)];
    bf16x8 pa1 = *(const bf16x8*)&pw[lr * 64 + SWZ8(lr, 32 + lq * 8)];
    // O += P V (round-2 verbatim)
    __builtin_amdgcn_s_setprio(1);
#pragma unroll
    for (int oc = 0; oc < 4; ++oc) {
      int rv = oc * 16 + lr;
      bf16x8 v0 = *(const bf16x8*)&lsV[cur][rv * 64 + SWZ8(rv, lq * 8)];
      bf16x8 v1 = *(const bf16x8*)&lsV[cur][rv * 64 + SWZ8(rv, 32 + lq * 8)];
      o[oc] = MFMA16(pa0, v0, o[oc]);
      o[oc] = MFMA16(pa1, v1, o[oc]);
    }
    __builtin_amdgcn_s_setprio(0);
    BARRIER();
  }
#undef STAGE
  // redistribute 1/l to output rows (lane q holds l for q = lane&15)
  float inv = 1.0f / l;
  float i0 = __shfl(inv, lq * 4 + 0, 64);
  float i1 = __shfl(inv, lq * 4 + 1, 64);
  float i2 = __shfl(inv, lq * 4 + 2, 64);
  float i3 = __shfl(inv, lq * 4 + 3, 64);
  int b = bh >> 3, h = bh & 7;
#pragma unroll
  for (int oc = 0; oc < 4; ++oc) {
    int q = qf * 64 + wave * 16 + lq * 4;
    int col = h * 64 + oc * 16 + lr;
    ao[((size_t)b * 2048 + q + 0) * 512 + col] = f2bf(o[oc][0] * i0);
    ao[((size_t)b * 2048 + q + 1) * 512 + col] = f2bf(o[oc][1] * i1);
    ao[((size_t)b * 2048 + q + 2) * 512 + col] = f2bf(o[oc][2] * i2);
    ao[((size_t)b * 2048 + q + 3) * 512 + col] = f2bf(o[oc][3] * i3);
  }
}

// ---------------- out GEMM: [8192,512] x [512,512] + bias -> fp32 ----------------
__global__ __launch_bounds__(256) void gemm_out(
    const u16* __restrict__ A, const u16* __restrict__ BT,
    const float* __restrict__ bias, float* __restrict__ out) {
  __shared__ u16 lsA[128 * 64], lsB[128 * 64];
  int m0 = blockIdx.x * 128, n0 = blockIdx.y * 128;
  int tid = threadIdx.x;
  int lane = tid & 63, wave = tid >> 6;
  int wm = (wave >> 1) * 64, wn = (wave & 1) * 64;
  int lr = lane & 15, lq = lane >> 4;
  f32x4 acc[4][4] = {};
  for (int kt = 0; kt < 8; ++kt) {
#pragma unroll
    for (int c = 0; c < 4; ++c) {
      int ci = c * 256 + tid;
      int row = ci >> 3, colb = ci & 7;
      int goff = kt * 64 + ((colb * 8) ^ ((row & 7) * 8));
      llds16(&lsA[ci * 8], &A[(size_t)(m0 + row) * 512 + goff]);
      llds16(&lsB[ci * 8], &BT[(size_t)(n0 + row) * 512 + goff]);
    }
    __syncthreads();
#pragma unroll
    for (int ks = 0; ks < 2; ++ks) {
      bf16x8 af[4], bfr[4];
#pragma unroll
      for (int i = 0; i < 4; ++i) {
        int ra = wm + i * 16 + lr;
        af[i] = *(const bf16x8*)&lsA[ra * 64 + SWZ8(ra, ks * 32 + lq * 8)];
        int rb = wn + i * 16 + lr;
        bfr[i] = *(const bf16x8*)&lsB[rb * 64 + SWZ8(rb, ks * 32 + lq * 8)];
      }
#pragma unroll
      for (int i = 0; i < 4; ++i)
#pragma unroll
        for (int j = 0; j < 4; ++j)
          acc[i][j] = MFMA16(af[i], bfr[j], acc[i][j]);
    }
    __syncthreads();
  }
#pragma unroll
  for (int j = 0; j < 4; ++j) {
    int gn = n0 + wn + j * 16 + lr;
    float bj = bias[gn];
#pragma unroll
    for (int i = 0; i < 4; ++i) {
      int gm = m0 + wm + i * 16 + lq * 4;
#pragma unroll
      for (int r = 0; r < 4; ++r)
        out[(size_t)(gm + r) * 512 + gn] = acc[i][j][r] + bj;
    }
  }
}

extern "C" void kernel_launch(void* const* d_in, const int* in_sizes, int n_in,
                              void* d_out, int out_size, void* d_ws, size_t ws_size,
                              hipStream_t stream) {
  const float* x = (const float*)d_in[0];
  const float* ln_g = (const float*)d_in[1];
  const float* ln_b = (const float*)d_in[2];
  const float* w_qkv = (const float*)d_in[3];
  const float* w_out = (const float*)d_in[4];
  const float* b_out = (const float*)d_in[5];
  float* out = (float*)d_out;
  char* ws = (char*)d_ws;

  u16* xn    = (u16*)(ws + 0);          //  8 MB  [8192][512] bf16
  u16* wqkvT = (u16*)(ws + 8388608);    //  1.5 MB [1536][512]
  u16* woutT = (u16*)(ws + 9961472);    //  0.5 MB [512][512]
  u16* qb    = (u16*)(ws + 10485760);   //  8 MB  [B,H,T,D]
  u16* kb    = (u16*)(ws + 18874368);   //  8 MB  [B,H,T,D]
  u16* vtb   = (u16*)(ws + 27262976);   //  8 MB  [B,H,D,T]
  u16* ao    = (u16*)(ws + 35651584);   //  8 MB  [8192][512]

  prep_weights<<<4096, 256, 0, stream>>>(w_qkv, w_out, wqkvT, woutT);
  ln_kernel<<<8192, 256, 0, stream>>>(x, ln_g, ln_b, xn);
  gemm_qkv<<<dim3(64, 12), 256, 0, stream>>>(xn, wqkvT, qb, kb, vtb);
  attn_kernel<<<1024, 256, 0, stream>>>(qb, kb, vtb, ao);
  gemm_out<<<dim3(64, 4), 256, 0, stream>>>(ao, woutT, b_out, out);
}